// Round 7
// baseline (99.856 us; speedup 1.0000x reference)
//
#include <hip/hip_runtime.h>
#include <math.h>

#define NCOL  6000
#define NV    1500      // float4 count per row
#define BLOCK 512
#define NWAVE 8         // BLOCK/64
#define RPB   8         // rows per block; 4096 % 8 == 0

typedef struct {
    float4 xp0, xp1, xp2;   // y_pred payload
    float4 xt0, xt1, xt2;   // y_true payload
    int4   mm0, mm1, mm2;   // mask payload
} Pay;

__device__ __forceinline__ float wave_max_f(float v) {
    #pragma unroll
    for (int off = 32; off > 0; off >>= 1) v = fmaxf(v, __shfl_xor(v, off, 64));
    return v;
}
__device__ __forceinline__ float wave_min_f(float v) {
    #pragma unroll
    for (int off = 32; off > 0; off >>= 1) v = fminf(v, __shfl_xor(v, off, 64));
    return v;
}
__device__ __forceinline__ int wave_sum_i(int v) {
    #pragma unroll
    for (int off = 32; off > 0; off >>= 1) v += __shfl_xor(v, off, 64);
    return v;
}
__device__ __forceinline__ double wave_sum_d(double v) {
    #pragma unroll
    for (int off = 32; off > 0; off >>= 1) v += __shfl_xor(v, off, 64);
    return v;
}

__device__ __forceinline__ void issue_row(
    const float4* __restrict__ yp4, const float4* __restrict__ yt4,
    const int4* __restrict__ mk4, size_t rbase, int tid, int vc2, Pay& P)
{
    const float4* p = yp4 + rbase;
    const float4* t = yt4 + rbase;
    const int4*   m = mk4 + rbase;
    P.xp0 = p[tid]; P.xp1 = p[tid + BLOCK]; P.xp2 = p[vc2];
    P.xt0 = t[tid]; P.xt1 = t[tid + BLOCK]; P.xt2 = t[vc2];
    P.mm0 = m[tid]; P.mm1 = m[tid + BLOCK]; P.mm2 = m[vc2];
}

// mask one component in place + accumulate row stats
#define DO_MASK(MM, XP, XT, C) do {                                   \
    bool  m_ = (MM).C > 0;                                            \
    float x_ = m_ ? (XP).C : -1e30f;                                  \
    float t_ = m_ ? (XT).C : -1e30f;                                  \
    tmin = fminf(tmin, m_ ? (XT).C : 1e30f);                          \
    (XP).C = x_; (XT).C = t_;                                         \
    maxp = fmaxf(maxp, x_); tmax = fmaxf(tmax, t_); cnt += m_;        \
} while (0)

// phase-2 accumulation for one component
#define DO_KL(XP, XT, C) do {                                         \
    float x_ = (XP).C, t_ = (XT).C;                                   \
    float ep_ = __expf(x_ - maxp);                                    \
    float z_  = scaled ? (t_ - tmin) * inv_s : t_;                    \
    z_ = fmaxf(z_, -1e30f);                                           \
    float e1_ = __expf(z_ - maxz);                                    \
    Zp += (double)ep_; S1 += (double)e1_;                             \
    S2 += (double)e1_ * (double)(z_ - x_);                            \
} while (0)

__device__ __forceinline__ void process_row(
    Pay P, int v2, int tid, int lane, int wid,
    float (*swf)[NWAVE], int* swi, double (*swd)[NWAVE],
    float* __restrict__ rowkl, int row)
{
    if (v2 >= NV) { P.mm2.x = 0; P.mm2.y = 0; P.mm2.z = 0; P.mm2.w = 0; }

    // ---- phase 1: mask in place, row stats ----
    float maxp = -1e30f, tmin = 1e30f, tmax = -1e30f;
    int cnt = 0;
    DO_MASK(P.mm0, P.xp0, P.xt0, x); DO_MASK(P.mm0, P.xp0, P.xt0, y);
    DO_MASK(P.mm0, P.xp0, P.xt0, z); DO_MASK(P.mm0, P.xp0, P.xt0, w);
    DO_MASK(P.mm1, P.xp1, P.xt1, x); DO_MASK(P.mm1, P.xp1, P.xt1, y);
    DO_MASK(P.mm1, P.xp1, P.xt1, z); DO_MASK(P.mm1, P.xp1, P.xt1, w);
    DO_MASK(P.mm2, P.xp2, P.xt2, x); DO_MASK(P.mm2, P.xp2, P.xt2, y);
    DO_MASK(P.mm2, P.xp2, P.xt2, z); DO_MASK(P.mm2, P.xp2, P.xt2, w);

    // ---- block-wide reduce of row stats ----
    maxp = wave_max_f(maxp);
    tmin = wave_min_f(tmin);
    tmax = wave_max_f(tmax);
    cnt  = wave_sum_i(cnt);
    if (lane == 0) { swf[0][wid] = maxp; swf[1][wid] = tmin; swf[2][wid] = tmax; swi[wid] = cnt; }
    __syncthreads();
    maxp = -1e30f; tmin = 1e30f; tmax = -1e30f; cnt = 0;
    #pragma unroll
    for (int j = 0; j < NWAVE; ++j) {
        maxp = fmaxf(maxp, swf[0][j]);
        tmin = fminf(tmin, swf[1][j]);
        tmax = fmaxf(tmax, swf[2][j]);
        cnt += swi[j];
    }

    const float rng   = tmax - tmin;
    const bool scaled = rng > 0.0f;
    const float inv_s = 1.0f / (rng + 1e-12f);
    const float maxz  = scaled ? rng * inv_s : tmax;

    // ---- phase 2: all from registers ----
    double Zp = 0.0, S1 = 0.0, S2 = 0.0;
    DO_KL(P.xp0, P.xt0, x); DO_KL(P.xp0, P.xt0, y);
    DO_KL(P.xp0, P.xt0, z); DO_KL(P.xp0, P.xt0, w);
    DO_KL(P.xp1, P.xt1, x); DO_KL(P.xp1, P.xt1, y);
    DO_KL(P.xp1, P.xt1, z); DO_KL(P.xp1, P.xt1, w);
    DO_KL(P.xp2, P.xt2, x); DO_KL(P.xp2, P.xt2, y);
    DO_KL(P.xp2, P.xt2, z); DO_KL(P.xp2, P.xt2, w);

    Zp = wave_sum_d(Zp);
    S1 = wave_sum_d(S1);
    S2 = wave_sum_d(S2);
    if (lane == 0) { swd[0][wid] = Zp; swd[1][wid] = S1; swd[2][wid] = S2; }
    __syncthreads();
    if (tid == 0) {
        double zp = 0.0, s1 = 0.0, s2 = 0.0;
        #pragma unroll
        for (int j = 0; j < NWAVE; ++j) { zp += swd[0][j]; s1 += swd[1][j]; s2 += swd[2][j]; }
        float val = 0.0f;
        if (cnt >= 2) {
            // kl_sum = S2/S1 + (maxp + log Zp - maxz - log S1)
            double kl = s2 / s1 + ((double)maxp + log(zp) - (double)maxz - log(s1));
            double v  = kl / (double)cnt;
            if (isfinite(v)) val = (float)v;
        }
        rowkl[row] = val;
    }
}

// min waves/EU = 4 -> 128-VGPR budget (need ~100 for the double buffer)
__global__ __launch_bounds__(BLOCK, 4) void row_kl_kernel(
    const float* __restrict__ yp, const float* __restrict__ yt,
    const int* __restrict__ mk, float* __restrict__ rowkl)
{
    __shared__ float  swf[3][NWAVE];
    __shared__ int    swi[NWAVE];
    __shared__ double swd[3][NWAVE];

    const int tid  = threadIdx.x;
    const int lane = tid & 63;
    const int wid  = tid >> 6;
    const int v2   = tid + 2 * BLOCK;
    const int vc2  = (v2 < NV) ? v2 : 0;

    const float4* yp4 = reinterpret_cast<const float4*>(yp);
    const float4* yt4 = reinterpret_cast<const float4*>(yt);
    const int4*   mk4 = reinterpret_cast<const int4*>(mk);

    const int row0 = blockIdx.x * RPB;

    Pay A, B;
    issue_row(yp4, yt4, mk4, (size_t)row0 * NV, tid, vc2, A);
    __builtin_amdgcn_sched_barrier(0);

    #pragma unroll 1
    for (int i = 0; i < RPB; i += 2) {
        // prefetch row i+1 while computing row i
        issue_row(yp4, yt4, mk4, (size_t)(row0 + i + 1) * NV, tid, vc2, B);
        __builtin_amdgcn_sched_barrier(0);
        process_row(A, v2, tid, lane, wid, swf, swi, swd, rowkl, row0 + i);

        // prefetch row i+2 while computing row i+1
        if (i + 2 < RPB)
            issue_row(yp4, yt4, mk4, (size_t)(row0 + i + 2) * NV, tid, vc2, A);
        __builtin_amdgcn_sched_barrier(0);
        process_row(B, v2, tid, lane, wid, swf, swi, swd, rowkl, row0 + i + 1);
    }
}

__global__ __launch_bounds__(256) void final_reduce_kernel(
    const float* __restrict__ rowkl, float* __restrict__ out, int nrows)
{
    __shared__ double swd[4];
    const int tid  = threadIdx.x;
    const int lane = tid & 63;
    const int wid  = tid >> 6;
    double acc = 0.0;
    for (int i = tid; i < nrows; i += 256) acc += (double)rowkl[i];
    acc = wave_sum_d(acc);
    if (lane == 0) swd[wid] = acc;
    __syncthreads();
    if (tid == 0) {
        double tot = 0.0;
        #pragma unroll
        for (int j = 0; j < 4; ++j) tot += swd[j];
        out[0] = (float)(tot / (double)nrows);
    }
}

extern "C" void kernel_launch(void* const* d_in, const int* in_sizes, int n_in,
                              void* d_out, int out_size, void* d_ws, size_t ws_size,
                              hipStream_t stream) {
    const float* y_pred = (const float*)d_in[0];
    const float* y_true = (const float*)d_in[1];
    const int*   masks  = (const int*)d_in[2];
    float* out = (float*)d_out;
    float* rowkl = (float*)d_ws;

    const int B = in_sizes[0] / NCOL;   // 4096 (divisible by RPB)

    row_kl_kernel<<<B / RPB, BLOCK, 0, stream>>>(y_pred, y_true, masks, rowkl);
    final_reduce_kernel<<<1, 256, 0, stream>>>(rowkl, out, B);
}

// Round 8
// 56.912 us; speedup vs baseline: 1.7546x; 1.7546x over previous
//
#include <hip/hip_runtime.h>
#include <math.h>

#define NCOL  6000
#define NV    1500      // float4 count per row
#define BLOCK 512
#define NWAVE 8         // BLOCK/64

typedef float f32x4 __attribute__((ext_vector_type(4)));
typedef int   i32x4 __attribute__((ext_vector_type(4)));

__device__ __forceinline__ void gld_f(f32x4& dst, const float* p) {
    asm volatile("global_load_dwordx4 %0, %1, off" : "=v"(dst) : "v"(p));
}
__device__ __forceinline__ void gld_i(i32x4& dst, const int* p) {
    asm volatile("global_load_dwordx4 %0, %1, off" : "=v"(dst) : "v"(p));
}

__device__ __forceinline__ float wave_max_f(float v) {
    #pragma unroll
    for (int off = 32; off > 0; off >>= 1) v = fmaxf(v, __shfl_xor(v, off, 64));
    return v;
}
__device__ __forceinline__ float wave_min_f(float v) {
    #pragma unroll
    for (int off = 32; off > 0; off >>= 1) v = fminf(v, __shfl_xor(v, off, 64));
    return v;
}
__device__ __forceinline__ int wave_sum_i(int v) {
    #pragma unroll
    for (int off = 32; off > 0; off >>= 1) v += __shfl_xor(v, off, 64);
    return v;
}
__device__ __forceinline__ double wave_sum_d(double v) {
    #pragma unroll
    for (int off = 32; off > 0; off >>= 1) v += __shfl_xor(v, off, 64);
    return v;
}

// mask one component in place + accumulate row stats
#define DO_MASK(MM, XP, XT, C) do {                                   \
    bool  m_ = (MM).C > 0;                                            \
    float x_ = m_ ? (XP).C : -1e30f;                                  \
    float t_ = m_ ? (XT).C : -1e30f;                                  \
    tmin = fminf(tmin, m_ ? (XT).C : 1e30f);                          \
    (XP).C = x_; (XT).C = t_;                                         \
    maxp = fmaxf(maxp, x_); tmax = fmaxf(tmax, t_); cnt += m_;        \
} while (0)

// phase-2 accumulation for one component
#define DO_KL(XP, XT, C) do {                                         \
    float x_ = (XP).C, t_ = (XT).C;                                   \
    float ep_ = __expf(x_ - maxp);                                    \
    float z_  = scaled ? (t_ - tmin) * inv_s : t_;                    \
    z_ = fmaxf(z_, -1e30f);                                           \
    float e1_ = __expf(z_ - maxz);                                    \
    Zp += (double)ep_; S1 += (double)e1_;                             \
    S2 += (double)e1_ * (double)(z_ - x_);                            \
} while (0)

__global__ __launch_bounds__(BLOCK) void row_kl_kernel(
    const float* __restrict__ yp, const float* __restrict__ yt,
    const int* __restrict__ mk, float* __restrict__ rowkl)
{
    __shared__ float  swf[3][NWAVE];
    __shared__ int    swi[NWAVE];
    __shared__ double swd[3][NWAVE];

    const int row  = blockIdx.x;
    const int tid  = threadIdx.x;
    const int lane = tid & 63;
    const int wid  = tid >> 6;

    const float* ypr = yp + (size_t)row * NCOL;
    const float* ytr = yt + (size_t)row * NCOL;
    const int*   mkr = mk + (size_t)row * NCOL;

    const int v2  = tid + 2 * BLOCK;
    const int vc2 = (v2 < NV) ? v2 : 0;   // clamp OOB tail (mask killed below)

    // ---- force 9 loads in flight: inline-asm global_load_dwordx4 ----
    f32x4 xp0, xp1, xp2, xt0, xt1, xt2;
    i32x4 mm0, mm1, mm2;
    gld_f(xp0, ypr + 4 * tid);
    gld_f(xp1, ypr + 4 * (tid + BLOCK));
    gld_f(xp2, ypr + 4 * vc2);
    gld_f(xt0, ytr + 4 * tid);
    gld_f(xt1, ytr + 4 * (tid + BLOCK));
    gld_f(xt2, ytr + 4 * vc2);
    gld_i(mm0, mkr + 4 * tid);
    gld_i(mm1, mkr + 4 * (tid + BLOCK));
    gld_i(mm2, mkr + 4 * vc2);
    asm volatile("s_waitcnt vmcnt(0)" ::: "memory");
    __builtin_amdgcn_sched_barrier(0);   // rule #18: no use hoisted above the wait

    if (v2 >= NV) { mm2.x = 0; mm2.y = 0; mm2.z = 0; mm2.w = 0; }

    // ---- phase 1: mask in place, row stats ----
    float maxp = -1e30f, tmin = 1e30f, tmax = -1e30f;
    int cnt = 0;
    DO_MASK(mm0, xp0, xt0, x); DO_MASK(mm0, xp0, xt0, y);
    DO_MASK(mm0, xp0, xt0, z); DO_MASK(mm0, xp0, xt0, w);
    DO_MASK(mm1, xp1, xt1, x); DO_MASK(mm1, xp1, xt1, y);
    DO_MASK(mm1, xp1, xt1, z); DO_MASK(mm1, xp1, xt1, w);
    DO_MASK(mm2, xp2, xt2, x); DO_MASK(mm2, xp2, xt2, y);
    DO_MASK(mm2, xp2, xt2, z); DO_MASK(mm2, xp2, xt2, w);

    // ---- block-wide reduce of row stats ----
    maxp = wave_max_f(maxp);
    tmin = wave_min_f(tmin);
    tmax = wave_max_f(tmax);
    cnt  = wave_sum_i(cnt);
    if (lane == 0) { swf[0][wid] = maxp; swf[1][wid] = tmin; swf[2][wid] = tmax; swi[wid] = cnt; }
    __syncthreads();
    maxp = -1e30f; tmin = 1e30f; tmax = -1e30f; cnt = 0;
    #pragma unroll
    for (int j = 0; j < NWAVE; ++j) {
        maxp = fmaxf(maxp, swf[0][j]);
        tmin = fminf(tmin, swf[1][j]);
        tmax = fmaxf(tmax, swf[2][j]);
        cnt += swi[j];
    }

    const float rng   = tmax - tmin;
    const bool scaled = rng > 0.0f;
    const float inv_s = 1.0f / (rng + 1e-12f);
    const float maxz  = scaled ? rng * inv_s : tmax;

    // ---- phase 2: everything from registers ----
    // Zp = sum exp(x-maxp); S1 = sum exp(z-maxz); S2 = sum exp(z-maxz)*(z-x)
    double Zp = 0.0, S1 = 0.0, S2 = 0.0;
    DO_KL(xp0, xt0, x); DO_KL(xp0, xt0, y); DO_KL(xp0, xt0, z); DO_KL(xp0, xt0, w);
    DO_KL(xp1, xt1, x); DO_KL(xp1, xt1, y); DO_KL(xp1, xt1, z); DO_KL(xp1, xt1, w);
    DO_KL(xp2, xt2, x); DO_KL(xp2, xt2, y); DO_KL(xp2, xt2, z); DO_KL(xp2, xt2, w);

    Zp = wave_sum_d(Zp);
    S1 = wave_sum_d(S1);
    S2 = wave_sum_d(S2);
    if (lane == 0) { swd[0][wid] = Zp; swd[1][wid] = S1; swd[2][wid] = S2; }
    __syncthreads();
    if (tid == 0) {
        double zp = 0.0, s1 = 0.0, s2 = 0.0;
        #pragma unroll
        for (int j = 0; j < NWAVE; ++j) { zp += swd[0][j]; s1 += swd[1][j]; s2 += swd[2][j]; }
        float val = 0.0f;
        if (cnt >= 2) {
            // kl_sum = S2/S1 + (maxp + log Zp - maxz - log S1)
            double kl = s2 / s1 + ((double)maxp + log(zp) - (double)maxz - log(s1));
            double v  = kl / (double)cnt;
            if (isfinite(v)) val = (float)v;
        }
        rowkl[row] = val;
    }
}

__global__ __launch_bounds__(256) void final_reduce_kernel(
    const float* __restrict__ rowkl, float* __restrict__ out, int nrows)
{
    __shared__ double swd[4];
    const int tid  = threadIdx.x;
    const int lane = tid & 63;
    const int wid  = tid >> 6;
    double acc = 0.0;
    for (int i = tid; i < nrows; i += 256) acc += (double)rowkl[i];
    acc = wave_sum_d(acc);
    if (lane == 0) swd[wid] = acc;
    __syncthreads();
    if (tid == 0) {
        double tot = 0.0;
        #pragma unroll
        for (int j = 0; j < 4; ++j) tot += swd[j];
        out[0] = (float)(tot / (double)nrows);
    }
}

extern "C" void kernel_launch(void* const* d_in, const int* in_sizes, int n_in,
                              void* d_out, int out_size, void* d_ws, size_t ws_size,
                              hipStream_t stream) {
    const float* y_pred = (const float*)d_in[0];
    const float* y_true = (const float*)d_in[1];
    const int*   masks  = (const int*)d_in[2];
    float* out = (float*)d_out;
    float* rowkl = (float*)d_ws;

    const int B = in_sizes[0] / NCOL;   // 4096

    row_kl_kernel<<<B, BLOCK, 0, stream>>>(y_pred, y_true, masks, rowkl);
    final_reduce_kernel<<<1, 256, 0, stream>>>(rowkl, out, B);
}